// Round 1
// baseline (1606.890 us; speedup 1.0000x reference)
//
#include <hip/hip_runtime.h>
#include <stdint.h>

typedef int   v4i __attribute__((ext_vector_type(4)));
typedef float v4f __attribute__((ext_vector_type(4)));

#define B_   2
#define S_   1024
#define HID_ 4096
#define NH_  32
#define NKV_ 8
#define HD_  128

__device__ __forceinline__ float qscale(float amax) {
    return amax > 0.0f ? amax / 127.0f : 1.0f;
}

__device__ __forceinline__ float wave_max(float v) {
#pragma unroll
    for (int o = 32; o >= 1; o >>= 1) v = fmaxf(v, __shfl_xor(v, o, 64));
    return v;
}

__device__ __forceinline__ void atomic_max_f32(float* p, float v) {
    atomicMax((unsigned int*)p, __float_as_uint(v)); // all values >= 0
}

__device__ __forceinline__ int q_clip(float x) {
    return (int)fminf(fmaxf(x, -128.0f), 127.0f);
}

// ---------------- amax reduction (vectorized, grid-stride) ----------------
__global__ __launch_bounds__(256) void amax_kernel(const float* __restrict__ x, long n4,
                                                   float* __restrict__ out) {
    long i = (long)blockIdx.x * 256 + threadIdx.x;
    long stride = (long)gridDim.x * 256;
    float m = 0.0f;
    for (; i < n4; i += stride) {
        v4f v = ((const v4f*)x)[i];
        m = fmaxf(m, fmaxf(fmaxf(fabsf(v[0]), fabsf(v[1])), fmaxf(fabsf(v[2]), fabsf(v[3]))));
    }
    m = wave_max(m);
    if ((threadIdx.x & 63) == 0) atomic_max_f32(out, m);
}

// ---------------- quantize f32 -> i8 (exact ref semantics: x/scale, rint, clip) ----
__global__ __launch_bounds__(256) void quant_kernel(const float* __restrict__ x, long n4,
                                                    const float* __restrict__ amax,
                                                    int8_t* __restrict__ out) {
    const float s = qscale(*amax);
    long i = (long)blockIdx.x * 256 + threadIdx.x;
    long stride = (long)gridDim.x * 256;
    for (; i < n4; i += stride) {
        v4f v = ((const v4f*)x)[i];
        int a = q_clip(rintf(v[0] / s));
        int b = q_clip(rintf(v[1] / s));
        int c = q_clip(rintf(v[2] / s));
        int d = q_clip(rintf(v[3] / s));
        uint32_t pk = (uint32_t)(uint8_t)a | ((uint32_t)(uint8_t)b << 8) |
                      ((uint32_t)(uint8_t)c << 16) | ((uint32_t)(uint8_t)d << 24);
        ((uint32_t*)out)[i] = pk;
    }
}

// ---------------- i8 GEMM: C[M][N] = (A[M][K] . B[N][K]^T) * sA*sB ----------------
#define BM 128
#define BN 128
#define BK 64
__global__ __launch_bounds__(256) void gemm_i8(const int8_t* __restrict__ A,
                                               const int8_t* __restrict__ Bw,
                                               float* __restrict__ C,
                                               int M, int N, int K,
                                               const float* __restrict__ amaxA,
                                               const float* __restrict__ amaxB) {
    __shared__ __align__(16) int8_t As[BM][80]; // 64 used + 16 pad (2-way bank aliasing = free)
    __shared__ __align__(16) int8_t Bs[BN][80];
    const float sAB = qscale(*amaxA) * qscale(*amaxB);
    const int tid = threadIdx.x;
    const int m0 = blockIdx.y * BM, n0 = blockIdx.x * BN;
    const int wave = tid >> 6, lane = tid & 63, l15 = lane & 15, l4 = lane >> 4;
    const int wr = wave >> 1, wc = wave & 1;
    v4i acc[4][4] = {};
    for (int k0 = 0; k0 < K; k0 += BK) {
#pragma unroll
        for (int i = 0; i < 2; i++) {
            int off = (tid + i * 256) * 16;
            int row = off >> 6, col = off & 63;
            *(v4i*)(&As[row][col]) = *(const v4i*)(A + (size_t)(m0 + row) * K + k0 + col);
            *(v4i*)(&Bs[row][col]) = *(const v4i*)(Bw + (size_t)(n0 + row) * K + k0 + col);
        }
        __syncthreads();
        v4i af[4], bf[4];
#pragma unroll
        for (int i = 0; i < 4; i++) af[i] = *(const v4i*)(&As[wr * 64 + i * 16 + l15][l4 * 16]);
#pragma unroll
        for (int j = 0; j < 4; j++) bf[j] = *(const v4i*)(&Bs[wc * 64 + j * 16 + l15][l4 * 16]);
#pragma unroll
        for (int i = 0; i < 4; i++)
#pragma unroll
            for (int j = 0; j < 4; j++)
                acc[i][j] = __builtin_amdgcn_mfma_i32_16x16x64_i8(af[i], bf[j], acc[i][j], 0, 0, 0);
        __syncthreads();
    }
#pragma unroll
    for (int i = 0; i < 4; i++) {
#pragma unroll
        for (int j = 0; j < 4; j++) {
            int r0 = m0 + wr * 64 + i * 16 + l4 * 4;
            int c = n0 + wc * 64 + j * 16 + l15;
#pragma unroll
            for (int t = 0; t < 4; t++)
                C[(size_t)(r0 + t) * N + c] = (float)acc[i][j][t] * sAB;
        }
    }
}

// ---------------- RoPE in-place on q_lin/k_lin + amax(q_rope), amax(k_rope) -------
__global__ __launch_bounds__(256) void rope_kernel(float* __restrict__ q, float* __restrict__ k,
                                                   const float* __restrict__ cosp,
                                                   const float* __restrict__ sinp,
                                                   float* __restrict__ amax_q,
                                                   float* __restrict__ amax_k) {
    const int bs = blockIdx.x; // b*S + s
    const float* cr = cosp + (size_t)bs * HD_;
    const float* sr = sinp + (size_t)bs * HD_;
    float* qr = q + (size_t)bs * (NH_ * HD_);
    float* kr = k + (size_t)bs * (NKV_ * HD_);
    const int tid = threadIdx.x;
    float mq = 0.0f, mk = 0.0f;
#pragma unroll
    for (int i = 0; i < 8; i++) { // 32 heads * 64 pairs / 256 threads
        int p = tid + i * 256;
        int hh = p >> 6, d = p & 63;
        float c1 = cr[d], s1 = sr[d], c2 = cr[d + 64], s2 = sr[d + 64];
        float x1 = qr[hh * HD_ + d], x2 = qr[hh * HD_ + d + 64];
        float o1 = x1 * c1 - x2 * s1;
        float o2 = x2 * c2 + x1 * s2;
        qr[hh * HD_ + d] = o1;
        qr[hh * HD_ + d + 64] = o2;
        mq = fmaxf(mq, fmaxf(fabsf(o1), fabsf(o2)));
    }
#pragma unroll
    for (int i = 0; i < 2; i++) { // 8 kv heads * 64 pairs / 256 threads
        int p = tid + i * 256;
        int hh = p >> 6, d = p & 63;
        float c1 = cr[d], s1 = sr[d], c2 = cr[d + 64], s2 = sr[d + 64];
        float x1 = kr[hh * HD_ + d], x2 = kr[hh * HD_ + d + 64];
        float o1 = x1 * c1 - x2 * s1;
        float o2 = x2 * c2 + x1 * s2;
        kr[hh * HD_ + d] = o1;
        kr[hh * HD_ + d + 64] = o2;
        mk = fmaxf(mk, fmaxf(fabsf(o1), fabsf(o2)));
    }
    mq = wave_max(mq);
    mk = wave_max(mk);
    if ((tid & 63) == 0) { atomic_max_f32(amax_q, mq); atomic_max_f32(amax_k, mk); }
}

// ---------------- transpose-quantize v: v_lin[b][s][hk*128+d] -> v8t[b][hk][d][s] ---
__global__ __launch_bounds__(256) void vtq_kernel(const float* __restrict__ v,
                                                  const float* __restrict__ amax,
                                                  int8_t* __restrict__ v8t) {
    __shared__ int8_t t[HD_][68];
    const int s0 = blockIdx.x * 64;
    const int bk = blockIdx.y; // b*NKV + hk
    const int b = bk >> 3, hk = bk & 7;
    const float s = qscale(*amax);
    const int tid = threadIdx.x;
#pragma unroll
    for (int i = 0; i < 32; i++) {
        int idx = tid + i * 256; // 64 s x 128 d
        int sr = idx >> 7, d = idx & 127;
        float x = v[(size_t)(b * S_ + s0 + sr) * (NKV_ * HD_) + hk * HD_ + d];
        t[d][sr] = (int8_t)q_clip(rintf(x / s));
    }
    __syncthreads();
#pragma unroll
    for (int i = 0; i < 8; i++) {
        int idx = (tid + i * 256) * 4; // 8192 bytes
        int d = idx >> 6, so = idx & 63;
        uint32_t val = *(uint32_t*)(&t[d][so]);
        *(uint32_t*)(v8t + ((size_t)(b * NKV_ + hk) * HD_ + d) * S_ + s0 + so) = val;
    }
}

// ---------------- QK^T (i8 MFMA) + causal softmax -> attn_weights + amax_p ---------
__global__ __launch_bounds__(256) void attn_score_softmax(const int8_t* __restrict__ q8,
                                                          const int8_t* __restrict__ k8,
                                                          float* __restrict__ attn,
                                                          const float* __restrict__ amax_q,
                                                          const float* __restrict__ amax_k,
                                                          float* __restrict__ amax_p) {
    __shared__ float scb[16][1028]; // padded: 2-way bank aliasing only
    const int q0 = blockIdx.x * 16;
    const int bh = blockIdx.y; // b*NH + h
    const int b = bh >> 5, h = bh & 31, hk = h >> 2;
    const int tid = threadIdx.x, wave = tid >> 6, lane = tid & 63;
    const int l15 = lane & 15, l4 = lane >> 4;
    const float scale = qscale(*amax_q) * qscale(*amax_k) * 0.08838834764831845f; // HD^-0.5

    const int8_t* qp = q8 + (size_t)(b * S_ + q0 + l15) * (NH_ * HD_) + h * HD_ + l4 * 16;
    v4i a0 = *(const v4i*)qp;
    v4i a1 = *(const v4i*)(qp + 64);
    const int8_t* kbase = k8 + (size_t)(b * S_) * (NKV_ * HD_) + hk * HD_ + l4 * 16;
#pragma unroll
    for (int f = 0; f < 16; f++) { // wave covers 256 k-columns
        int cb = wave * 256 + f * 16;
        const int8_t* kp = kbase + (size_t)(cb + l15) * (NKV_ * HD_);
        v4i b0 = *(const v4i*)kp;
        v4i b1 = *(const v4i*)(kp + 64);
        v4i c = {};
        c = __builtin_amdgcn_mfma_i32_16x16x64_i8(a0, b0, c, 0, 0, 0);
        c = __builtin_amdgcn_mfma_i32_16x16x64_i8(a1, b1, c, 0, 0, 0);
#pragma unroll
        for (int t = 0; t < 4; t++)
            scb[l4 * 4 + t][cb + l15] = (float)c[t] * scale; // exact: |i32| < 2^24
    }
    __syncthreads();
    // softmax: 16 rows x 16 lanes each (analytic causal == additive -FLT_MAX mask)
    const int row = tid >> 4, lc = tid & 15;
    const int qg = q0 + row;
    const int nvalid = qg + 1;
    float m = -3.4e38f;
    for (int i = lc; i < nvalid; i += 16) m = fmaxf(m, scb[row][i]);
#pragma unroll
    for (int o = 8; o >= 1; o >>= 1) m = fmaxf(m, __shfl_xor(m, o, 64));
    float sum = 0.0f;
    for (int i = lc; i < nvalid; i += 16) {
        float e = __expf(scb[row][i] - m);
        sum += e;
        scb[row][i] = e;
    }
#pragma unroll
    for (int o = 8; o >= 1; o >>= 1) sum += __shfl_xor(sum, o, 64);
    float inv = 1.0f / sum;
    if (lc == 0) atomic_max_f32(amax_p, inv); // row max p = 1/sum; global max = 1.0 (row 0)
    float* orow = attn + ((size_t)bh * S_ + qg) * S_;
    for (int i = lc; i < S_; i += 16)
        orow[i] = (i < nvalid) ? scb[row][i] * inv : 0.0f;
}

// ---------------- PV: quantize p on the fly, i8 MFMA vs v8t, fused amax(out) -------
__global__ __launch_bounds__(256) void attn_pv(const float* __restrict__ attn,
                                               const int8_t* __restrict__ v8t,
                                               float* __restrict__ out,
                                               const float* __restrict__ amax_p,
                                               const float* __restrict__ amax_v,
                                               float* __restrict__ amax_o) {
    __shared__ __align__(16) int8_t p8[16][1040]; // padded, 16B-aligned rows
    const int q0 = blockIdx.x * 16;
    const int bh = blockIdx.y;
    const int b = bh >> 5, h = bh & 31, hk = h >> 2;
    const int tid = threadIdx.x;
    const float sp = qscale(*amax_p), sv = qscale(*amax_v);
    const float rsp = 1.0f / sp;
    const float* prow = attn + ((size_t)bh * S_ + q0) * S_;
#pragma unroll
    for (int i = 0; i < 16; i++) {
        int idx = (tid + i * 256) * 4; // 16 x 1024 elements
        int r = idx >> 10, c = idx & 1023;
        v4f v = *(const v4f*)(prow + (size_t)r * S_ + c);
        int a = q_clip(rintf(v[0] * rsp));
        int bq = q_clip(rintf(v[1] * rsp));
        int cq = q_clip(rintf(v[2] * rsp));
        int d = q_clip(rintf(v[3] * rsp));
        uint32_t pk = (uint32_t)(uint8_t)a | ((uint32_t)(uint8_t)bq << 8) |
                      ((uint32_t)(uint8_t)cq << 16) | ((uint32_t)(uint8_t)d << 24);
        *(uint32_t*)(&p8[r][c]) = pk;
    }
    __syncthreads();
    const int wave = tid >> 6, lane = tid & 63, l15 = lane & 15, l4 = lane >> 4;
    const int8_t* vb = v8t + ((size_t)(b * NKV_ + hk) * HD_ + wave * 32 + l15) * S_ + l4 * 16;
    v4i acc0 = {}, acc1 = {};
    for (int k0 = 0; k0 < S_; k0 += 64) {
        v4i a = *(const v4i*)(&p8[l15][k0 + l4 * 16]);
        v4i b0 = *(const v4i*)(vb + k0);
        v4i b1 = *(const v4i*)(vb + (size_t)16 * S_ + k0);
        acc0 = __builtin_amdgcn_mfma_i32_16x16x64_i8(a, b0, acc0, 0, 0, 0);
        acc1 = __builtin_amdgcn_mfma_i32_16x16x64_i8(a, b1, acc1, 0, 0, 0);
    }
    const float sab = sp * sv;
    float lm = 0.0f;
#pragma unroll
    for (int t = 0; t < 4; t++) {
        int r = q0 + l4 * 4 + t;
        float f0 = (float)acc0[t] * sab; // exact: |i32| < 2^24
        float f1 = (float)acc1[t] * sab;
        size_t base = ((size_t)b * S_ + r) * (NH_ * HD_) + h * HD_ + wave * 32;
        out[base + l15] = f0;
        out[base + 16 + l15] = f1;
        lm = fmaxf(lm, fmaxf(fabsf(f0), fabsf(f1)));
    }
    lm = wave_max(lm);
    if (lane == 0) atomic_max_f32(amax_o, lm);
}

// =============================== launcher =====================================
extern "C" void kernel_launch(void* const* d_in, const int* in_sizes, int n_in,
                              void* d_out, int out_size, void* d_ws, size_t ws_size,
                              hipStream_t stream) {
    const float* hidden = (const float*)d_in[0];
    const float* cosp = (const float*)d_in[1];
    const float* sinp = (const float*)d_in[2];
    // d_in[3] = attention_mask (causal; computed analytically)
    const float* wq = (const float*)d_in[4];
    const float* wk = (const float*)d_in[5];
    const float* wv = (const float*)d_in[6];
    const float* wo = (const float*)d_in[7];

    float* out0 = (float*)d_out;                               // attn_output (B,S,HID)
    float* attnw = out0 + (size_t)B_ * S_ * HID_;              // attn_weights (B,NH,S,S)

    char* ws = (char*)d_ws;
    float* scal = (float*)ws; // [0]=x [1]=wq [2]=wk [3]=wv [4]=wo [5]=q [6]=k [7]=v [8]=p [9]=ao
    size_t off = 256;
    auto alloc = [&](size_t bytes) {
        char* p = ws + off;
        off += (bytes + 255) & ~(size_t)255;
        return p;
    };
    int8_t* x8 = (int8_t*)alloc((size_t)B_ * S_ * HID_);                 // 8 MB
    int8_t* wq8 = (int8_t*)alloc((size_t)NH_ * HD_ * HID_);              // 16 MB
    int8_t* wk8 = (int8_t*)alloc((size_t)NKV_ * HD_ * HID_);             // 4 MB
    int8_t* wv8 = (int8_t*)alloc((size_t)NKV_ * HD_ * HID_);             // 4 MB
    int8_t* wo8 = (int8_t*)alloc((size_t)HID_ * NH_ * HD_);              // 16 MB
    float* q_lin = (float*)alloc((size_t)B_ * S_ * NH_ * HD_ * 4);       // 32 MB
    float* k_lin = (float*)alloc((size_t)B_ * S_ * NKV_ * HD_ * 4);      // 8 MB
    float* v_lin = (float*)alloc((size_t)B_ * S_ * NKV_ * HD_ * 4);      // 8 MB
    int8_t* q8 = (int8_t*)alloc((size_t)B_ * S_ * NH_ * HD_);            // 8 MB
    int8_t* k8 = (int8_t*)alloc((size_t)B_ * S_ * NKV_ * HD_);           // 2 MB
    int8_t* v8t = (int8_t*)alloc((size_t)B_ * NKV_ * HD_ * S_);          // 2 MB
    float* ctx = q_lin;   // reuse: q_lin dead after q8 quantize; PV writes here
    int8_t* ao8 = x8;     // reuse: x8 dead after QKV GEMMs

    hipMemsetAsync(scal, 0, 64, stream);

    const long nH4 = (long)B_ * S_ * HID_ / 4;          // hidden / q_lin / ctx
    const long nWq4 = (long)NH_ * HD_ * HID_ / 4;       // wq / wo
    const long nWk4 = (long)NKV_ * HD_ * HID_ / 4;      // wk / wv
    const long nK4 = (long)B_ * S_ * NKV_ * HD_ / 4;    // k_lin / v_lin

    // amax of raw inputs
    amax_kernel<<<1024, 256, 0, stream>>>(hidden, nH4, scal + 0);
    amax_kernel<<<1024, 256, 0, stream>>>(wq, nWq4, scal + 1);
    amax_kernel<<<1024, 256, 0, stream>>>(wk, nWk4, scal + 2);
    amax_kernel<<<1024, 256, 0, stream>>>(wv, nWk4, scal + 3);
    amax_kernel<<<1024, 256, 0, stream>>>(wo, nWq4, scal + 4);
    // quantize
    quant_kernel<<<1024, 256, 0, stream>>>(hidden, nH4, scal + 0, x8);
    quant_kernel<<<1024, 256, 0, stream>>>(wq, nWq4, scal + 1, wq8);
    quant_kernel<<<1024, 256, 0, stream>>>(wk, nWk4, scal + 2, wk8);
    quant_kernel<<<1024, 256, 0, stream>>>(wv, nWk4, scal + 3, wv8);
    quant_kernel<<<1024, 256, 0, stream>>>(wo, nWq4, scal + 4, wo8);
    // QKV projections (i8 GEMM)
    gemm_i8<<<dim3(HID_ / BN, (B_ * S_) / BM), 256, 0, stream>>>(
        x8, wq8, q_lin, B_ * S_, NH_ * HD_, HID_, scal + 0, scal + 1);
    gemm_i8<<<dim3((NKV_ * HD_) / BN, (B_ * S_) / BM), 256, 0, stream>>>(
        x8, wk8, k_lin, B_ * S_, NKV_ * HD_, HID_, scal + 0, scal + 2);
    gemm_i8<<<dim3((NKV_ * HD_) / BN, (B_ * S_) / BM), 256, 0, stream>>>(
        x8, wv8, v_lin, B_ * S_, NKV_ * HD_, HID_, scal + 0, scal + 3);
    // RoPE (in place) + amax(q_rope), amax(k_rope); amax(v)
    rope_kernel<<<B_ * S_, 256, 0, stream>>>(q_lin, k_lin, cosp, sinp, scal + 5, scal + 6);
    amax_kernel<<<1024, 256, 0, stream>>>(v_lin, nK4, scal + 7);
    // quantize q/k; transpose-quantize v
    quant_kernel<<<1024, 256, 0, stream>>>(q_lin, nH4, scal + 5, q8);
    quant_kernel<<<1024, 256, 0, stream>>>(k_lin, nK4, scal + 6, k8);
    vtq_kernel<<<dim3(S_ / 64, B_ * NKV_), 256, 0, stream>>>(v_lin, scal + 7, v8t);
    // QK^T + softmax -> attn_weights output + amax_p
    attn_score_softmax<<<dim3(S_ / 16, B_ * NH_), 256, 0, stream>>>(
        q8, k8, attnw, scal + 5, scal + 6, scal + 8);
    // PV -> ctx + amax(ctx)
    attn_pv<<<dim3(S_ / 16, B_ * NH_), 256, 0, stream>>>(
        attnw, v8t, ctx, scal + 8, scal + 7, scal + 9);
    // O projection
    quant_kernel<<<1024, 256, 0, stream>>>(ctx, nH4, scal + 9, ao8);
    gemm_i8<<<dim3(HID_ / BN, (B_ * S_) / BM), 256, 0, stream>>>(
        ao8, wo8, out0, B_ * S_, HID_, NH_ * HD_, scal + 9, scal + 4);
}

// Round 2
// 1331.162 us; speedup vs baseline: 1.2071x; 1.2071x over previous
//
#include <hip/hip_runtime.h>
#include <stdint.h>

typedef int   v4i __attribute__((ext_vector_type(4)));
typedef float v4f __attribute__((ext_vector_type(4)));
typedef uint32_t u32;

#define B_   2
#define S_   1024
#define HID_ 4096
#define NH_  32
#define NKV_ 8
#define HD_  128

__device__ __forceinline__ float qscale(float amax) {
    return amax > 0.0f ? amax / 127.0f : 1.0f;
}

__device__ __forceinline__ float wave_max(float v) {
#pragma unroll
    for (int o = 32; o >= 1; o >>= 1) v = fmaxf(v, __shfl_xor(v, o, 64));
    return v;
}

__device__ __forceinline__ void atomic_max_f32(float* p, float v) {
    atomicMax((unsigned int*)p, __float_as_uint(v)); // all values >= 0
}

__device__ __forceinline__ int q_clip(float x) {
    return (int)fminf(fmaxf(x, -128.0f), 127.0f);
}

__device__ __forceinline__ void gload_lds16(const void* g, void* l) {
    __builtin_amdgcn_global_load_lds(
        (const __attribute__((address_space(1))) void*)g,
        (__attribute__((address_space(3))) void*)l, 16, 0, 0);
}

// ---------------- amax reduction (vectorized, grid-stride) ----------------
__global__ __launch_bounds__(256) void amax_kernel(const float* __restrict__ x, long n4,
                                                   float* __restrict__ out) {
    long i = (long)blockIdx.x * 256 + threadIdx.x;
    long stride = (long)gridDim.x * 256;
    float m = 0.0f;
    for (; i < n4; i += stride) {
        v4f v = ((const v4f*)x)[i];
        m = fmaxf(m, fmaxf(fmaxf(fabsf(v[0]), fabsf(v[1])), fmaxf(fabsf(v[2]), fabsf(v[3]))));
    }
    m = wave_max(m);
    if ((threadIdx.x & 63) == 0) atomic_max_f32(out, m);
}

// ---------------- quantize f32 -> i8 (exact ref semantics) ----------------
__global__ __launch_bounds__(256) void quant_kernel(const float* __restrict__ x, long n4,
                                                    const float* __restrict__ amax,
                                                    int8_t* __restrict__ out) {
    const float s = qscale(*amax);
    long i = (long)blockIdx.x * 256 + threadIdx.x;
    long stride = (long)gridDim.x * 256;
    for (; i < n4; i += stride) {
        v4f v = ((const v4f*)x)[i];
        int a = q_clip(rintf(v[0] / s));
        int b = q_clip(rintf(v[1] / s));
        int c = q_clip(rintf(v[2] / s));
        int d = q_clip(rintf(v[3] / s));
        uint32_t pk = (uint32_t)(uint8_t)a | ((uint32_t)(uint8_t)b << 8) |
                      ((uint32_t)(uint8_t)c << 16) | ((uint32_t)(uint8_t)d << 24);
        ((uint32_t*)out)[i] = pk;
    }
}

// ---------------- i8 GEMM with global_load_lds staging (m97 structure) -----------
// C[M][N] = (A[M][K] . B[N][K]^T) * sA*sB ; blockIdx.z selects B0/C0 vs B1/C1
#define BM 128
#define BN 128
#define BK 64
__global__ __launch_bounds__(256) void gemm_i8(const int8_t* __restrict__ A,
                                               const int8_t* __restrict__ B0,
                                               const int8_t* __restrict__ B1,
                                               float* __restrict__ C0,
                                               float* __restrict__ C1,
                                               int M, int N, int K,
                                               const float* __restrict__ amaxA,
                                               const float* __restrict__ amaxB0,
                                               const float* __restrict__ amaxB1) {
    __shared__ __align__(16) int8_t As[BM * BK]; // linear [row][64] - required by global_load_lds
    __shared__ __align__(16) int8_t Bs[BN * BK];
    const int8_t* Bw = blockIdx.z ? B1 : B0;
    float* C = blockIdx.z ? C1 : C0;
    const float sAB = qscale(*amaxA) * qscale(blockIdx.z ? *amaxB1 : *amaxB0);
    const int tid = threadIdx.x;
    const int m0 = blockIdx.y * BM, n0 = blockIdx.x * BN;
    const int wave = tid >> 6, lane = tid & 63, l15 = lane & 15, l4 = lane >> 4;
    const int wr = wave >> 1, wc = wave & 1;
    const int srow = lane >> 2;          // row within 16-row chunk
    const int scol = (lane & 3) * 16;    // byte col within 64B row
    v4i acc[4][4] = {};
    for (int k0 = 0; k0 < K; k0 += BK) {
#pragma unroll
        for (int c = 0; c < 2; c++) {
            int chunk = wave + c * 4;    // 8 chunks of 1KB each per tile
            int row = chunk * 16 + srow;
            gload_lds16(A + (size_t)(m0 + row) * K + k0 + scol, &As[chunk * 1024 + lane * 16]);
            gload_lds16(Bw + (size_t)(n0 + row) * K + k0 + scol, &Bs[chunk * 1024 + lane * 16]);
        }
        __syncthreads();
        v4i af[4], bf[4];
#pragma unroll
        for (int i = 0; i < 4; i++)
            af[i] = *(const v4i*)(&As[(wr * 64 + i * 16 + l15) * 64 + l4 * 16]);
#pragma unroll
        for (int j = 0; j < 4; j++)
            bf[j] = *(const v4i*)(&Bs[(wc * 64 + j * 16 + l15) * 64 + l4 * 16]);
#pragma unroll
        for (int i = 0; i < 4; i++)
#pragma unroll
            for (int j = 0; j < 4; j++)
                acc[i][j] = __builtin_amdgcn_mfma_i32_16x16x64_i8(af[i], bf[j], acc[i][j], 0, 0, 0);
        __syncthreads();
    }
#pragma unroll
    for (int i = 0; i < 4; i++) {
#pragma unroll
        for (int j = 0; j < 4; j++) {
            int r0 = m0 + wr * 64 + i * 16 + l4 * 4;
            int c = n0 + wc * 64 + j * 16 + l15;
#pragma unroll
            for (int t = 0; t < 4; t++)
                C[(size_t)(r0 + t) * N + c] = (float)acc[i][j][t] * sAB;
        }
    }
}

// ---------------- RoPE in-place + amax(q_rope), amax(k_rope) ----------------
__global__ __launch_bounds__(256) void rope_kernel(float* __restrict__ q, float* __restrict__ k,
                                                   const float* __restrict__ cosp,
                                                   const float* __restrict__ sinp,
                                                   float* __restrict__ amax_q,
                                                   float* __restrict__ amax_k) {
    const int bs = blockIdx.x;
    const float* cr = cosp + (size_t)bs * HD_;
    const float* sr = sinp + (size_t)bs * HD_;
    float* qr = q + (size_t)bs * (NH_ * HD_);
    float* kr = k + (size_t)bs * (NKV_ * HD_);
    const int tid = threadIdx.x;
    float mq = 0.0f, mk = 0.0f;
#pragma unroll
    for (int i = 0; i < 8; i++) {
        int p = tid + i * 256;
        int hh = p >> 6, d = p & 63;
        float c1 = cr[d], s1 = sr[d], c2 = cr[d + 64], s2 = sr[d + 64];
        float x1 = qr[hh * HD_ + d], x2 = qr[hh * HD_ + d + 64];
        float o1 = x1 * c1 - x2 * s1;
        float o2 = x2 * c2 + x1 * s2;
        qr[hh * HD_ + d] = o1;
        qr[hh * HD_ + d + 64] = o2;
        mq = fmaxf(mq, fmaxf(fabsf(o1), fabsf(o2)));
    }
#pragma unroll
    for (int i = 0; i < 2; i++) {
        int p = tid + i * 256;
        int hh = p >> 6, d = p & 63;
        float c1 = cr[d], s1 = sr[d], c2 = cr[d + 64], s2 = sr[d + 64];
        float x1 = kr[hh * HD_ + d], x2 = kr[hh * HD_ + d + 64];
        float o1 = x1 * c1 - x2 * s1;
        float o2 = x2 * c2 + x1 * s2;
        kr[hh * HD_ + d] = o1;
        kr[hh * HD_ + d + 64] = o2;
        mk = fmaxf(mk, fmaxf(fabsf(o1), fabsf(o2)));
    }
    mq = wave_max(mq);
    mk = wave_max(mk);
    if ((tid & 63) == 0) { atomic_max_f32(amax_q, mq); atomic_max_f32(amax_k, mk); }
}

// ---------------- transpose-quantize v -> v8t[b][hk][d][s] ----------------
__global__ __launch_bounds__(256) void vtq_kernel(const float* __restrict__ v,
                                                  const float* __restrict__ amax,
                                                  int8_t* __restrict__ v8t) {
    __shared__ int8_t t[HD_][68];
    const int s0 = blockIdx.x * 64;
    const int bk = blockIdx.y;
    const int b = bk >> 3, hk = bk & 7;
    const float s = qscale(*amax);
    const int tid = threadIdx.x;
#pragma unroll
    for (int i = 0; i < 32; i++) {
        int idx = tid + i * 256;
        int sr = idx >> 7, d = idx & 127;
        float x = v[(size_t)(b * S_ + s0 + sr) * (NKV_ * HD_) + hk * HD_ + d];
        t[d][sr] = (int8_t)q_clip(rintf(x / s));
    }
    __syncthreads();
#pragma unroll
    for (int i = 0; i < 8; i++) {
        int idx = (tid + i * 256) * 4;
        int d = idx >> 6, so = idx & 63;
        uint32_t val = *(uint32_t*)(&t[d][so]);
        *(uint32_t*)(v8t + ((size_t)(b * NKV_ + hk) * HD_ + d) * S_ + s0 + so) = val;
    }
}

// ---------------- fused QK^T -> softmax -> attn_weights + quantized P -> PV -------
// Swapped-operand MFMA: mfma(K, Q) puts one q-row per lane (col=l15), k values
// 4-consecutive per register quad -> lane-local softmax + dwordx4 attnw stores.
// amax(P) == 1.0 exactly (row 0 softmaxes one element) -> scale_p = 1/127 constant.
__global__ __launch_bounds__(256) void attn_fused(const int8_t* __restrict__ q8,
                                                  const int8_t* __restrict__ k8,
                                                  const int8_t* __restrict__ v8t,
                                                  float* __restrict__ attnw,
                                                  float* __restrict__ ctx,
                                                  const float* __restrict__ amax_q,
                                                  const float* __restrict__ amax_k,
                                                  const float* __restrict__ amax_v,
                                                  float* __restrict__ amax_o) {
    __shared__ __align__(16) int8_t p8[16 * 1072]; // stride 1072 = 16-aligned, bank-friendly
    __shared__ float pm[4][16];
    __shared__ float ps[4][16];
    const int q0 = blockIdx.x * 16;
    const int bh = blockIdx.y; // b*NH + h
    const int b = bh >> 5, h = bh & 31, hk = h >> 2;
    const int tid = threadIdx.x, wave = tid >> 6, lane = tid & 63;
    const int l15 = lane & 15, l4 = lane >> 4;
    const int cb = wave * 256; // this wave's k-chunk
    const float scale = qscale(*amax_q) * qscale(*amax_k) * 0.08838834764831845f;
    const int qg = q0 + l15;   // this lane's q row
    const int kmax = q0 + 15;  // last causally-valid k in this block

    const int8_t* qp = q8 + (size_t)(b * S_ + qg) * (NH_ * HD_) + h * HD_ + l4 * 16;
    v4i qf0 = *(const v4i*)qp;
    v4i qf1 = *(const v4i*)(qp + 64);
    const int8_t* kb8 = k8 + (size_t)(b * S_) * (NKV_ * HD_) + hk * HD_ + l4 * 16;

    // phase A: scores for this wave's 256-k chunk, register-resident
    float s[16][4];
#pragma unroll
    for (int f = 0; f < 16; f++) {
        int kb = cb + f * 16;
        if (kb <= kmax) { // wave-uniform branch
            const int8_t* kp = kb8 + (size_t)(kb + l15) * (NKV_ * HD_);
            v4i a0 = *(const v4i*)kp;
            v4i a1 = *(const v4i*)(kp + 64);
            v4i c = {};
            c = __builtin_amdgcn_mfma_i32_16x16x64_i8(a0, qf0, c, 0, 0, 0);
            c = __builtin_amdgcn_mfma_i32_16x16x64_i8(a1, qf1, c, 0, 0, 0);
#pragma unroll
            for (int t = 0; t < 4; t++) s[f][t] = (float)c[t] * scale; // exact: |i32| < 2^24
        } else {
#pragma unroll
            for (int t = 0; t < 4; t++) s[f][t] = -3.0e38f;
        }
    }
    // row max: lane-local over valid k, then cross-l4 shfl, then cross-wave LDS
    float m = -3.0e38f;
#pragma unroll
    for (int f = 0; f < 16; f++)
#pragma unroll
        for (int t = 0; t < 4; t++) {
            int k = cb + f * 16 + l4 * 4 + t;
            if (k <= qg) m = fmaxf(m, s[f][t]);
        }
    m = fmaxf(m, __shfl_xor(m, 16, 64));
    m = fmaxf(m, __shfl_xor(m, 32, 64));
    if (l4 == 0) pm[wave][l15] = m;
    __syncthreads();
    m = fmaxf(fmaxf(pm[0][l15], pm[1][l15]), fmaxf(pm[2][l15], pm[3][l15]));
    // exp + row sum
    float sum = 0.0f;
#pragma unroll
    for (int f = 0; f < 16; f++)
#pragma unroll
        for (int t = 0; t < 4; t++) {
            int k = cb + f * 16 + l4 * 4 + t;
            float e = (k <= qg) ? __expf(s[f][t] - m) : 0.0f;
            s[f][t] = e;
            sum += e;
        }
    sum += __shfl_xor(sum, 16, 64);
    sum += __shfl_xor(sum, 32, 64);
    if (l4 == 0) ps[wave][l15] = sum;
    __syncthreads();
    sum = (ps[0][l15] + ps[1][l15]) + (ps[2][l15] + ps[3][l15]);
    const float inv = 1.0f / sum;
    const float sp = 1.0f / 127.0f; // amax(P) == 1.0 exactly
    const float rsp = 1.0f / sp;
    // write attn_weights (dwordx4) + quantize P into LDS
    float* orow = attnw + ((size_t)bh * S_ + qg) * S_;
#pragma unroll
    for (int f = 0; f < 16; f++) {
        int kb = cb + f * 16 + l4 * 4;
        v4f pv;
        u32 pk = 0;
#pragma unroll
        for (int t = 0; t < 4; t++) {
            float p = s[f][t] * inv;
            pv[t] = p;
            int qv = q_clip(rintf(p * rsp));
            pk |= (u32)(uint8_t)qv << (8 * t);
        }
        *(v4f*)(orow + kb) = pv;
        *(u32*)(&p8[l15 * 1072 + kb]) = pk;
    }
    __syncthreads();
    // PV: A = P (LDS), B = V^T (global, L2-warm), skip fully-masked k-steps
    const int8_t* vb = v8t + ((size_t)(b * NKV_ + hk) * HD_ + wave * 32 + l15) * S_;
    v4i acc0 = {}, acc1 = {};
    const int nsteps = (q0 + 16 + 63) >> 6;
    for (int ks = 0; ks < nsteps; ks++) {
        int k0 = ks * 64;
        v4i a = *(const v4i*)(&p8[l15 * 1072 + k0 + l4 * 16]);
        v4i b0 = *(const v4i*)(vb + k0 + l4 * 16);
        v4i b1 = *(const v4i*)(vb + (size_t)16 * S_ + k0 + l4 * 16);
        acc0 = __builtin_amdgcn_mfma_i32_16x16x64_i8(a, b0, acc0, 0, 0, 0);
        acc1 = __builtin_amdgcn_mfma_i32_16x16x64_i8(a, b1, acc1, 0, 0, 0);
    }
    const float sab = sp * qscale(*amax_v);
    float lm = 0.0f;
#pragma unroll
    for (int t = 0; t < 4; t++) {
        int r = q0 + l4 * 4 + t;
        float f0 = (float)acc0[t] * sab; // exact: |i32| <= 127*127*1024 < 2^24
        float f1 = (float)acc1[t] * sab;
        size_t base = ((size_t)b * S_ + r) * (NH_ * HD_) + h * HD_ + wave * 32;
        ctx[base + l15] = f0;
        ctx[base + 16 + l15] = f1;
        lm = fmaxf(lm, fmaxf(fabsf(f0), fabsf(f1)));
    }
    lm = wave_max(lm);
    if (lane == 0) atomic_max_f32(amax_o, lm);
}

// =============================== launcher =====================================
extern "C" void kernel_launch(void* const* d_in, const int* in_sizes, int n_in,
                              void* d_out, int out_size, void* d_ws, size_t ws_size,
                              hipStream_t stream) {
    const float* hidden = (const float*)d_in[0];
    const float* cosp = (const float*)d_in[1];
    const float* sinp = (const float*)d_in[2];
    // d_in[3] = attention_mask (causal; computed analytically)
    const float* wq = (const float*)d_in[4];
    const float* wk = (const float*)d_in[5];
    const float* wv = (const float*)d_in[6];
    const float* wo = (const float*)d_in[7];

    float* out0 = (float*)d_out;                  // attn_output (B,S,HID)
    float* attnw = out0 + (size_t)B_ * S_ * HID_; // attn_weights (B,NH,S,S)

    char* ws = (char*)d_ws;
    float* scal = (float*)ws; // [0]=x [1]=wq [2]=wk [3]=wv [4]=wo [5]=q [6]=k [7]=v [9]=ao
    size_t off = 256;
    auto alloc = [&](size_t bytes) {
        char* p = ws + off;
        off += (bytes + 255) & ~(size_t)255;
        return p;
    };
    int8_t* x8 = (int8_t*)alloc((size_t)B_ * S_ * HID_);
    int8_t* wq8 = (int8_t*)alloc((size_t)NH_ * HD_ * HID_);
    int8_t* wk8 = (int8_t*)alloc((size_t)NKV_ * HD_ * HID_);
    int8_t* wv8 = (int8_t*)alloc((size_t)NKV_ * HD_ * HID_);
    int8_t* wo8 = (int8_t*)alloc((size_t)HID_ * NH_ * HD_);
    float* q_lin = (float*)alloc((size_t)B_ * S_ * NH_ * HD_ * 4);
    float* k_lin = (float*)alloc((size_t)B_ * S_ * NKV_ * HD_ * 4);
    float* v_lin = (float*)alloc((size_t)B_ * S_ * NKV_ * HD_ * 4);
    int8_t* q8 = (int8_t*)alloc((size_t)B_ * S_ * NH_ * HD_);
    int8_t* k8 = (int8_t*)alloc((size_t)B_ * S_ * NKV_ * HD_);
    int8_t* v8t = (int8_t*)alloc((size_t)B_ * NKV_ * HD_ * S_);
    float* ctx = q_lin; // reuse: q_lin dead after q8 quantize
    int8_t* ao8 = x8;   // reuse: x8 dead after QKV GEMMs

    hipMemsetAsync(scal, 0, 64, stream);

    const long nH4 = (long)B_ * S_ * HID_ / 4;
    const long nWq4 = (long)NH_ * HD_ * HID_ / 4;
    const long nWk4 = (long)NKV_ * HD_ * HID_ / 4;
    const long nK4 = (long)B_ * S_ * NKV_ * HD_ / 4;

    amax_kernel<<<1024, 256, 0, stream>>>(hidden, nH4, scal + 0);
    amax_kernel<<<1024, 256, 0, stream>>>(wq, nWq4, scal + 1);
    amax_kernel<<<1024, 256, 0, stream>>>(wk, nWk4, scal + 2);
    amax_kernel<<<1024, 256, 0, stream>>>(wv, nWk4, scal + 3);
    amax_kernel<<<1024, 256, 0, stream>>>(wo, nWq4, scal + 4);
    quant_kernel<<<1024, 256, 0, stream>>>(hidden, nH4, scal + 0, x8);
    quant_kernel<<<1024, 256, 0, stream>>>(wq, nWq4, scal + 1, wq8);
    quant_kernel<<<1024, 256, 0, stream>>>(wk, nWk4, scal + 2, wk8);
    quant_kernel<<<1024, 256, 0, stream>>>(wv, nWk4, scal + 3, wv8);
    quant_kernel<<<1024, 256, 0, stream>>>(wo, nWq4, scal + 4, wo8);
    // Q projection
    gemm_i8<<<dim3(NH_ * HD_ / BN, (B_ * S_) / BM, 1), 256, 0, stream>>>(
        x8, wq8, wq8, q_lin, q_lin, B_ * S_, NH_ * HD_, HID_, scal + 0, scal + 1, scal + 1);
    // K and V projections z-batched (256 blocks instead of 2x128)
    gemm_i8<<<dim3(NKV_ * HD_ / BN, (B_ * S_) / BM, 2), 256, 0, stream>>>(
        x8, wk8, wv8, k_lin, v_lin, B_ * S_, NKV_ * HD_, HID_, scal + 0, scal + 2, scal + 3);
    rope_kernel<<<B_ * S_, 256, 0, stream>>>(q_lin, k_lin, cosp, sinp, scal + 5, scal + 6);
    amax_kernel<<<1024, 256, 0, stream>>>(v_lin, nK4, scal + 7);
    quant_kernel<<<1024, 256, 0, stream>>>(q_lin, nH4, scal + 5, q8);
    quant_kernel<<<1024, 256, 0, stream>>>(k_lin, nK4, scal + 6, k8);
    vtq_kernel<<<dim3(S_ / 64, B_ * NKV_), 256, 0, stream>>>(v_lin, scal + 7, v8t);
    // fused QK^T + softmax + attn_weights write + P-quant + PV + amax(ctx)
    attn_fused<<<dim3(S_ / 16, B_ * NH_), 256, 0, stream>>>(
        q8, k8, v8t, attnw, ctx, scal + 5, scal + 6, scal + 7, scal + 9);
    // O projection
    quant_kernel<<<1024, 256, 0, stream>>>(ctx, nH4, scal + 9, ao8);
    gemm_i8<<<dim3(HID_ / BN, (B_ * S_) / BM, 1), 256, 0, stream>>>(
        ao8, wo8, wo8, out0, out0, B_ * S_, HID_, NH_ * HD_, scal + 9, scal + 4, scal + 4);
}